// Round 4
// baseline (257.874 us; speedup 1.0000x reference)
//
#include <hip/hip_runtime.h>
#include <math.h>

// Problem constants (B=8, C=192, H=W=32)
#define BB 8
#define CC 192
#define LL 1024
#define RT 8192         // total rows = BB*LL
#define DI 384          // d_inner
#define DT_RANK 12
#define NS 16           // D_STATE
#define NSEG 16
#define SEGL 64

// ---------------------------------------------------------------------------
// K1: W2[j,c'] = sum_c in_proj_w[j,c]*proj_w[c,c'];  bias2[j] = in_proj_w[j,:]·proj_b
__global__ void fuse_w_kernel(const float* __restrict__ in_proj_w,
                              const float* __restrict__ proj_w,
                              const float* __restrict__ proj_b,
                              float* __restrict__ W2, float* __restrict__ bias2) {
    int j = blockIdx.x;
    int cp = threadIdx.x;
    __shared__ float wrow[CC];
    wrow[cp] = in_proj_w[j * CC + cp];
    __syncthreads();
    float acc = 0.f;
#pragma unroll 4
    for (int c = 0; c < CC; ++c) acc = fmaf(wrow[c], proj_w[c * CC + cp], acc);
    W2[j * CC + cp] = acc;
    if (cp == 0) {
        float b = 0.f;
        for (int c = 0; c < CC; ++c) b = fmaf(wrow[c], proj_b[c], b);
        bias2[j] = b;
    }
}

// ---------------------------------------------------------------------------
// K2: xzT[j, row] = sum_c x[b, c, l] * W2[j, c] + bias2[j]   (row = b*1024+l)
// 128 rows x 96 j tile, 8x6 microtile, 256 threads. grid (64, 8).
__global__ __launch_bounds__(256) void gemm_xz(const float* __restrict__ x,
                                               const float* __restrict__ W2,
                                               const float* __restrict__ bias2,
                                               float* __restrict__ xzT) {
    __shared__ float As[16][132];  // [k][row]
    __shared__ float Bs[16][100];  // [k][j]
    int r0 = blockIdx.x * 128;
    int j0 = blockIdx.y * 96;
    int b  = r0 >> 10;
    int l0 = r0 & 1023;
    int tid = threadIdx.x;
    int tx = tid & 15;   // row octet
    int ty = tid >> 4;   // j sextet
    float acc[6][8] = {};
    const float* xb = x + b * CC * LL;
    for (int k0 = 0; k0 < CC; k0 += 16) {
#pragma unroll
        for (int it = 0; it < 2; ++it) {     // A: 16k x 128row = 512 float4
            int idx = tid + it * 256;
            int k = idx >> 5, l4 = (idx & 31) * 4;
            *(float4*)&As[k][l4] = *(const float4*)&xb[(k0 + k) * LL + l0 + l4];
        }
#pragma unroll
        for (int it = 0; it < 2; ++it) {     // B: 96j x 16k = 384 float4
            int idx = tid + it * 256;
            if (idx < 384) {
                int j = idx >> 2, kq = (idx & 3) * 4;
                float4 v = *(const float4*)&W2[(j0 + j) * CC + k0 + kq];
                Bs[kq + 0][j] = v.x; Bs[kq + 1][j] = v.y;
                Bs[kq + 2][j] = v.z; Bs[kq + 3][j] = v.w;
            }
        }
        __syncthreads();
#pragma unroll
        for (int k = 0; k < 16; ++k) {
            float4 a0 = *(const float4*)&As[k][tx * 8];
            float4 a1 = *(const float4*)&As[k][tx * 8 + 4];
            float ar[8] = {a0.x, a0.y, a0.z, a0.w, a1.x, a1.y, a1.z, a1.w};
            float br[6];
#pragma unroll
            for (int q = 0; q < 6; ++q) br[q] = Bs[k][ty * 6 + q];
#pragma unroll
            for (int jc = 0; jc < 6; ++jc)
#pragma unroll
                for (int rc = 0; rc < 8; ++rc)
                    acc[jc][rc] = fmaf(br[jc], ar[rc], acc[jc][rc]);
        }
        __syncthreads();
    }
#pragma unroll
    for (int jc = 0; jc < 6; ++jc) {
        int j = j0 + ty * 6 + jc;
        float bval = bias2[j];
        float4 o0, o1;
        o0.x = acc[jc][0] + bval; o0.y = acc[jc][1] + bval;
        o0.z = acc[jc][2] + bval; o0.w = acc[jc][3] + bval;
        o1.x = acc[jc][4] + bval; o1.y = acc[jc][5] + bval;
        o1.z = acc[jc][6] + bval; o1.w = acc[jc][7] + bval;
        *(float4*)&xzT[j * RT + r0 + tx * 8]     = o0;
        *(float4*)&xzT[j * RT + r0 + tx * 8 + 4] = o1;
    }
}

// ---------------------------------------------------------------------------
// K3: d<384: causal depthwise conv (k=4) + silu -> xcT.
//     d>=384: silu(z) in place in xzT (becomes zsT).
__global__ void conv_silu(float* __restrict__ xzT,
                          const float* __restrict__ conv_w,
                          const float* __restrict__ conv_b,
                          float* __restrict__ xcT) {
    int q = blockIdx.x * 256 + threadIdx.x;
    int d = q >> 11;
    int rq = (q & 2047) << 2;
    if (d < DI) {
        int l0 = rq & 1023;
        const float* base = xzT + d * RT + rq;
        float4 cur = *(const float4*)base;
        float4 prev = make_float4(0.f, 0.f, 0.f, 0.f);
        if (l0 != 0) prev = *(const float4*)(base - 4);
        float w0 = conv_w[d * 4 + 0], w1 = conv_w[d * 4 + 1];
        float w2 = conv_w[d * 4 + 2], w3 = conv_w[d * 4 + 3];
        float bb = conv_b[d];
        float a0 = bb + w3 * cur.x + w2 * prev.w + w1 * prev.z + w0 * prev.y;
        float a1 = bb + w3 * cur.y + w2 * cur.x  + w1 * prev.w + w0 * prev.z;
        float a2 = bb + w3 * cur.z + w2 * cur.y  + w1 * cur.x  + w0 * prev.w;
        float a3 = bb + w3 * cur.w + w2 * cur.z  + w1 * cur.y  + w0 * cur.x;
        float4 o;
        o.x = __fdividef(a0, 1.f + __expf(-a0));
        o.y = __fdividef(a1, 1.f + __expf(-a1));
        o.z = __fdividef(a2, 1.f + __expf(-a2));
        o.w = __fdividef(a3, 1.f + __expf(-a3));
        *(float4*)(xcT + d * RT + rq) = o;
    } else {
        float* base = xzT + d * RT + rq;
        float4 v = *(const float4*)base;
        float4 o;
        o.x = __fdividef(v.x, 1.f + __expf(-v.x));
        o.y = __fdividef(v.y, 1.f + __expf(-v.y));
        o.z = __fdividef(v.z, 1.f + __expf(-v.z));
        o.w = __fdividef(v.w, 1.f + __expf(-v.w));
        *(float4*)base = o;
    }
}

// ---------------------------------------------------------------------------
// K4a: skinny GEMM  xdT[m][row] = sum_k xproj_w[m][k] * xcT[k][row]
__global__ __launch_bounds__(512) void xproj_gemm(const float* __restrict__ xcT,
                                                  const float* __restrict__ aw,
                                                  float* __restrict__ xdT) {
    __shared__ float Bs[32][64];
    int col0 = blockIdx.x * 64;
    int tid = threadIdx.x;
    int col = tid & 63, mg = tid >> 6;
    int mb = blockIdx.y * 24 + mg * 3;
    const float* a0 = aw + min(mb + 0, 43) * DI;
    const float* a1 = aw + min(mb + 1, 43) * DI;
    const float* a2 = aw + min(mb + 2, 43) * DI;
    float acc0 = 0.f, acc1 = 0.f, acc2 = 0.f;
    int ks = tid >> 4, c4 = (tid & 15) * 4;
    for (int k0 = 0; k0 < DI; k0 += 32) {
        *(float4*)&Bs[ks][c4] = *(const float4*)&xcT[(k0 + ks) * RT + col0 + c4];
        __syncthreads();
#pragma unroll
        for (int k = 0; k < 32; ++k) {
            float bv = Bs[k][col];
            acc0 = fmaf(a0[k0 + k], bv, acc0);
            acc1 = fmaf(a1[k0 + k], bv, acc1);
            acc2 = fmaf(a2[k0 + k], bv, acc2);
        }
        __syncthreads();
    }
    if (mb + 0 < 44) xdT[(mb + 0) * RT + col0 + col] = acc0;
    if (mb + 1 < 44) xdT[(mb + 1) * RT + col0 + col] = acc1;
    if (mb + 2 < 44) xdT[(mb + 2) * RT + col0 + col] = acc2;
}

// ---------------------------------------------------------------------------
// K4b: dtT[d][row] = softplus(sum_r dtrT[r][row] * w[d][r] + b[d])
__global__ __launch_bounds__(512) void dtproj_kernel(const float* __restrict__ dtrT,
                                                     const float* __restrict__ w,
                                                     const float* __restrict__ bvec,
                                                     float* __restrict__ dtT) {
    int col0 = blockIdx.x * 64;
    int tid = threadIdx.x;
    int col = tid & 63, mg = tid >> 6;
    int d0 = blockIdx.y * 128 + mg * 16;
    float rv[DT_RANK];
#pragma unroll
    for (int rr = 0; rr < DT_RANK; ++rr) rv[rr] = dtrT[rr * RT + col0 + col];
#pragma unroll
    for (int dd = 0; dd < 16; ++dd) {
        int d = d0 + dd;
        float acc = bvec[d];
#pragma unroll
        for (int rr = 0; rr < DT_RANK; ++rr) acc = fmaf(rv[rr], w[d * DT_RANK + rr], acc);
        float sp = fmaxf(acc, 0.f) + __logf(1.f + __expf(-fabsf(acc)));
        dtT[d * RT + col0 + col] = sp;
    }
}

// ---------------------------------------------------------------------------
// K5a: per-segment scan from h=0; emit P = prod(dA), Hf = final h.
__global__ __launch_bounds__(256) void scan_part1(const float* __restrict__ dtT,
                                                  const float* __restrict__ xcT,
                                                  const float* __restrict__ BT,
                                                  const float* __restrict__ A_log,
                                                  float* __restrict__ P,
                                                  float* __restrict__ Hf) {
    __shared__ float dt_s[16][17], g_s[16][17], B_s[16][17];
    int seg = blockIdx.x, d0 = blockIdx.y * 16, b = blockIdx.z;
    int row0 = b * LL + seg * SEGL;
    int tid = threadIdx.x;
    int lane = tid & 63;
    int n = lane & 15;
    int dl = ((tid >> 6) << 2) | (lane >> 4);
    int tdd = tid >> 4, ti = tid & 15;
    float a = -__expf(A_log[(d0 + dl) * NS + n]);
    float h = 0.f, Pacc = 1.f;
    for (int ch = 0; ch < 4; ++ch) {
        int r = row0 + ch * 16;
        float dtv = dtT[(d0 + tdd) * RT + r + ti];
        float xv  = xcT[(d0 + tdd) * RT + r + ti];
        dt_s[tdd][ti] = dtv;
        g_s[tdd][ti]  = dtv * xv;
        B_s[tdd][ti]  = BT[tdd * RT + r + ti];
        __syncthreads();
#pragma unroll
        for (int i = 0; i < 16; ++i) {
            float e = __expf(dt_s[dl][i] * a);
            Pacc *= e;
            h = fmaf(e, h, g_s[dl][i] * B_s[n][i]);
        }
        __syncthreads();
    }
    int idx = ((seg * BB + b) * DI + d0 + dl) * NS + n;
    P[idx] = Pacc;
    Hf[idx] = h;
}

// ---------------------------------------------------------------------------
// K5b: scan the 16 segment summaries; write h_init into P in place.
__global__ __launch_bounds__(256) void scan_mid(float* __restrict__ P,
                                                const float* __restrict__ Hf) {
    int t = blockIdx.x * 256 + threadIdx.x;   // 49152 = BB*DI*NS
    float h = 0.f;
#pragma unroll
    for (int s = 0; s < NSEG; ++s) {
        int off = s * (BB * DI * NS) + t;
        float p = P[off], f = Hf[off];
        P[off] = h;
        h = fmaf(p, h, f);
    }
}

// ---------------------------------------------------------------------------
// K5c: rescan each segment from h_init. Per-step h*C goes to LDS (off the
// VALU pipe); per-chunk 16-wide n-reduction by the thread that staged (and
// thus holds in registers) xc/zs for the element it writes.
// yT aliases dtT (each block reads its dt tile before overwriting it).
__global__ __launch_bounds__(256) void scan_part2(const float* __restrict__ dtT,
                                                  const float* __restrict__ xcT,
                                                  const float* __restrict__ BT,
                                                  const float* __restrict__ CT,
                                                  const float* __restrict__ zsT,
                                                  const float* __restrict__ Hinit,
                                                  const float* __restrict__ A_log,
                                                  const float* __restrict__ Dp,
                                                  float* __restrict__ yT) {
    __shared__ float dt_s[16][17], g_s[16][17], B_s[16][17], C_s[16][17];
    __shared__ float hc_s[16][16][17];   // [dl][i][n]; strides 272/17 -> 2-way banks (free)
    int seg = blockIdx.x, d0 = blockIdx.y * 16, b = blockIdx.z;
    int row0 = b * LL + seg * SEGL;
    int tid = threadIdx.x;
    int lane = tid & 63;
    int n = lane & 15;
    int dl = ((tid >> 6) << 2) | (lane >> 4);
    int d = d0 + dl;
    int tdd = tid >> 4, ti = tid & 15;
    float a = -__expf(A_log[d * NS + n]);
    float Dpw = Dp[d0 + tdd];            // for the writer role (tdd,ti)
    float h = Hinit[((seg * BB + b) * DI + d) * NS + n];
    for (int ch = 0; ch < 4; ++ch) {
        int r = row0 + ch * 16;
        float dtv = dtT[(d0 + tdd) * RT + r + ti];
        float xv  = xcT[(d0 + tdd) * RT + r + ti];
        float zsv = zsT[(d0 + tdd) * RT + r + ti];
        dt_s[tdd][ti] = dtv;
        g_s[tdd][ti]  = dtv * xv;
        B_s[tdd][ti]  = BT[tdd * RT + r + ti];
        C_s[tdd][ti]  = CT[tdd * RT + r + ti];
        __syncthreads();
#pragma unroll
        for (int i = 0; i < 16; ++i) {
            float e = __expf(dt_s[dl][i] * a);
            h = fmaf(e, h, g_s[dl][i] * B_s[n][i]);
            hc_s[dl][i][n] = h * C_s[n][i];
        }
        __syncthreads();
        // thread (tdd,ti) owns element (d=d0+tdd, row=r+ti); xv/zsv in regs
        float s0 = 0.f, s1 = 0.f, s2 = 0.f, s3 = 0.f;
#pragma unroll
        for (int q = 0; q < 4; ++q) {
            s0 += hc_s[tdd][ti][q];
            s1 += hc_s[tdd][ti][4 + q];
            s2 += hc_s[tdd][ti][8 + q];
            s3 += hc_s[tdd][ti][12 + q];
        }
        float sum = (s0 + s1) + (s2 + s3);
        yT[(d0 + tdd) * RT + r + ti] = fmaf(xv, Dpw, sum) * zsv;
    }
}

// ---------------------------------------------------------------------------
// K6: out[b, c, l] = sum_d yT[d, row] * out_w[c, d]
// 64 rows x 96 c tile, 4x6 microtile, 256 threads. grid (128, 2).
__global__ __launch_bounds__(256) void gemm_out(const float* __restrict__ yT,
                                                const float* __restrict__ out_w,
                                                float* __restrict__ out) {
    __shared__ float As[16][68];   // [k][row]
    __shared__ float Bs[16][100];  // [k][c]
    int r0 = blockIdx.x * 64;
    int c0 = blockIdx.y * 96;
    int b = r0 >> 10, l0 = r0 & 1023;
    int tid = threadIdx.x;
    int tx = tid & 15;   // row quad
    int ty = tid >> 4;   // c sextet
    float acc[6][4] = {};
    for (int k0 = 0; k0 < DI; k0 += 16) {
        {   // A: yT[k0+k, r0+r..] -> As[k][r]
            int k = tid >> 4, r4 = (tid & 15) * 4;
            *(float4*)&As[k][r4] = *(const float4*)&yT[(k0 + k) * RT + r0 + r4];
        }
#pragma unroll
        for (int it = 0; it < 2; ++it) {   // B: 96c x 16k = 384 float4
            int idx = tid + it * 256;
            if (idx < 384) {
                int c = idx >> 2, kq = (idx & 3) * 4;
                float4 v = *(const float4*)&out_w[(c0 + c) * DI + k0 + kq];
                Bs[kq + 0][c] = v.x; Bs[kq + 1][c] = v.y;
                Bs[kq + 2][c] = v.z; Bs[kq + 3][c] = v.w;
            }
        }
        __syncthreads();
#pragma unroll
        for (int k = 0; k < 16; ++k) {
            float4 av = *(const float4*)&As[k][tx * 4];
            float ar[4] = {av.x, av.y, av.z, av.w};
            float br[6];
#pragma unroll
            for (int q = 0; q < 6; ++q) br[q] = Bs[k][ty * 6 + q];
#pragma unroll
            for (int jc = 0; jc < 6; ++jc)
#pragma unroll
                for (int rc = 0; rc < 4; ++rc)
                    acc[jc][rc] = fmaf(br[jc], ar[rc], acc[jc][rc]);
        }
        __syncthreads();
    }
    float* ob = out + b * CC * LL;
#pragma unroll
    for (int jc = 0; jc < 6; ++jc) {
        int c = c0 + ty * 6 + jc;
        float4 o;
        o.x = acc[jc][0]; o.y = acc[jc][1]; o.z = acc[jc][2]; o.w = acc[jc][3];
        *(float4*)&ob[c * LL + l0 + tx * 4] = o;
    }
}

// ---------------------------------------------------------------------------
extern "C" void kernel_launch(void* const* d_in, const int* in_sizes, int n_in,
                              void* d_out, int out_size, void* d_ws, size_t ws_size,
                              hipStream_t stream) {
    const float* x         = (const float*)d_in[0];
    const float* proj_w    = (const float*)d_in[1];
    const float* proj_b    = (const float*)d_in[2];
    const float* in_proj_w = (const float*)d_in[3];
    const float* conv_w    = (const float*)d_in[4];
    const float* conv_b    = (const float*)d_in[5];
    const float* xproj_w   = (const float*)d_in[6];
    const float* dtproj_w  = (const float*)d_in[7];
    const float* dtproj_b  = (const float*)d_in[8];
    const float* A_log     = (const float*)d_in[9];
    const float* Dp        = (const float*)d_in[10];
    const float* out_w     = (const float*)d_in[11];
    float* out = (float*)d_out;

    float* ws    = (float*)d_ws;
    float* W2    = ws;                    // 147456
    float* bias2 = W2 + 147456;           // 768
    float* xzT   = bias2 + 768;           // 768*8192 = 6291456
    float* xcT   = xzT + 6291456;         // 3145728
    float* dtT   = xcT + 3145728;         // 3145728 (aliased as yT)
    float* xdT   = dtT + 3145728;         // 44*8192 = 360448
    float* P     = xdT + 360448;          // 786432
    float* Hf    = P + 786432;            // 786432
    float* dtrT = xdT;                    // rows 0-11
    float* BT   = xdT + 12 * RT;          // rows 12-27
    float* CT   = xdT + 28 * RT;          // rows 28-43
    float* zsT  = xzT + DI * RT;          // z half, silu'd in place by conv_silu
    float* yT   = dtT;

    fuse_w_kernel<<<768, 192, 0, stream>>>(in_proj_w, proj_w, proj_b, W2, bias2);
    gemm_xz<<<dim3(64, 8), 256, 0, stream>>>(x, W2, bias2, xzT);
    conv_silu<<<6144, 256, 0, stream>>>(xzT, conv_w, conv_b, xcT);
    xproj_gemm<<<dim3(128, 2), 512, 0, stream>>>(xcT, xproj_w, xdT);
    dtproj_kernel<<<dim3(128, 3), 512, 0, stream>>>(dtrT, dtproj_w, dtproj_b, dtT);
    scan_part1<<<dim3(16, 24, 8), 256, 0, stream>>>(dtT, xcT, BT, A_log, P, Hf);
    scan_mid<<<192, 256, 0, stream>>>(P, Hf);
    scan_part2<<<dim3(16, 24, 8), 256, 0, stream>>>(dtT, xcT, BT, CT, zsT, P, A_log, Dp, yT);
    gemm_out<<<dim3(128, 2), 256, 0, stream>>>(yT, out_w, out);
}

// Round 5
// 242.912 us; speedup vs baseline: 1.0616x; 1.0616x over previous
//
#include <hip/hip_runtime.h>
#include <math.h>

// Problem constants (B=8, C=192, H=W=32)
#define BB 8
#define CC 192
#define LL 1024
#define RT 8192         // total rows = BB*LL
#define DI 384          // d_inner
#define DT_RANK 12
#define NS 16           // D_STATE
#define NSEG 16
#define SEGL 64

// ---------------------------------------------------------------------------
// K1: W2[j,c'] = sum_c in_proj_w[j,c]*proj_w[c,c'];  bias2[j] = in_proj_w[j,:]·proj_b
__global__ void fuse_w_kernel(const float* __restrict__ in_proj_w,
                              const float* __restrict__ proj_w,
                              const float* __restrict__ proj_b,
                              float* __restrict__ W2, float* __restrict__ bias2) {
    int j = blockIdx.x;
    int cp = threadIdx.x;
    __shared__ float wrow[CC];
    wrow[cp] = in_proj_w[j * CC + cp];
    __syncthreads();
    float acc = 0.f;
#pragma unroll 4
    for (int c = 0; c < CC; ++c) acc = fmaf(wrow[c], proj_w[c * CC + cp], acc);
    W2[j * CC + cp] = acc;
    if (cp == 0) {
        float b = 0.f;
        for (int c = 0; c < CC; ++c) b = fmaf(wrow[c], proj_b[c], b);
        bias2[j] = b;
    }
}

// ---------------------------------------------------------------------------
// K2: xzT[j, row] = sum_c x[b, c, l] * W2[j, c] + bias2[j]   (row = b*1024+l)
// 128 rows x 96 j tile, 8x6 microtile, 256 threads. grid (64, 8).
__global__ __launch_bounds__(256) void gemm_xz(const float* __restrict__ x,
                                               const float* __restrict__ W2,
                                               const float* __restrict__ bias2,
                                               float* __restrict__ xzT) {
    __shared__ float As[16][132];  // [k][row]
    __shared__ float Bs[16][100];  // [k][j]
    int r0 = blockIdx.x * 128;
    int j0 = blockIdx.y * 96;
    int b  = r0 >> 10;
    int l0 = r0 & 1023;
    int tid = threadIdx.x;
    int tx = tid & 15;   // row octet
    int ty = tid >> 4;   // j sextet
    float acc[6][8] = {};
    const float* xb = x + b * CC * LL;
    for (int k0 = 0; k0 < CC; k0 += 16) {
#pragma unroll
        for (int it = 0; it < 2; ++it) {     // A: 16k x 128row = 512 float4
            int idx = tid + it * 256;
            int k = idx >> 5, l4 = (idx & 31) * 4;
            *(float4*)&As[k][l4] = *(const float4*)&xb[(k0 + k) * LL + l0 + l4];
        }
#pragma unroll
        for (int it = 0; it < 2; ++it) {     // B: 96j x 16k = 384 float4
            int idx = tid + it * 256;
            if (idx < 384) {
                int j = idx >> 2, kq = (idx & 3) * 4;
                float4 v = *(const float4*)&W2[(j0 + j) * CC + k0 + kq];
                Bs[kq + 0][j] = v.x; Bs[kq + 1][j] = v.y;
                Bs[kq + 2][j] = v.z; Bs[kq + 3][j] = v.w;
            }
        }
        __syncthreads();
#pragma unroll
        for (int k = 0; k < 16; ++k) {
            float4 a0 = *(const float4*)&As[k][tx * 8];
            float4 a1 = *(const float4*)&As[k][tx * 8 + 4];
            float ar[8] = {a0.x, a0.y, a0.z, a0.w, a1.x, a1.y, a1.z, a1.w};
            float br[6];
#pragma unroll
            for (int q = 0; q < 6; ++q) br[q] = Bs[k][ty * 6 + q];
#pragma unroll
            for (int jc = 0; jc < 6; ++jc)
#pragma unroll
                for (int rc = 0; rc < 8; ++rc)
                    acc[jc][rc] = fmaf(br[jc], ar[rc], acc[jc][rc]);
        }
        __syncthreads();
    }
#pragma unroll
    for (int jc = 0; jc < 6; ++jc) {
        int j = j0 + ty * 6 + jc;
        float bval = bias2[j];
        float4 o0, o1;
        o0.x = acc[jc][0] + bval; o0.y = acc[jc][1] + bval;
        o0.z = acc[jc][2] + bval; o0.w = acc[jc][3] + bval;
        o1.x = acc[jc][4] + bval; o1.y = acc[jc][5] + bval;
        o1.z = acc[jc][6] + bval; o1.w = acc[jc][7] + bval;
        *(float4*)&xzT[j * RT + r0 + tx * 8]     = o0;
        *(float4*)&xzT[j * RT + r0 + tx * 8 + 4] = o1;
    }
}

// ---------------------------------------------------------------------------
// K3: d<384: causal depthwise conv (k=4) + silu -> xcT.
//     d>=384: silu(z) in place in xzT (becomes zsT).
__global__ void conv_silu(float* __restrict__ xzT,
                          const float* __restrict__ conv_w,
                          const float* __restrict__ conv_b,
                          float* __restrict__ xcT) {
    int q = blockIdx.x * 256 + threadIdx.x;
    int d = q >> 11;
    int rq = (q & 2047) << 2;
    if (d < DI) {
        int l0 = rq & 1023;
        const float* base = xzT + d * RT + rq;
        float4 cur = *(const float4*)base;
        float4 prev = make_float4(0.f, 0.f, 0.f, 0.f);
        if (l0 != 0) prev = *(const float4*)(base - 4);
        float w0 = conv_w[d * 4 + 0], w1 = conv_w[d * 4 + 1];
        float w2 = conv_w[d * 4 + 2], w3 = conv_w[d * 4 + 3];
        float bb = conv_b[d];
        float a0 = bb + w3 * cur.x + w2 * prev.w + w1 * prev.z + w0 * prev.y;
        float a1 = bb + w3 * cur.y + w2 * cur.x  + w1 * prev.w + w0 * prev.z;
        float a2 = bb + w3 * cur.z + w2 * cur.y  + w1 * cur.x  + w0 * prev.w;
        float a3 = bb + w3 * cur.w + w2 * cur.z  + w1 * cur.y  + w0 * cur.x;
        float4 o;
        o.x = __fdividef(a0, 1.f + __expf(-a0));
        o.y = __fdividef(a1, 1.f + __expf(-a1));
        o.z = __fdividef(a2, 1.f + __expf(-a2));
        o.w = __fdividef(a3, 1.f + __expf(-a3));
        *(float4*)(xcT + d * RT + rq) = o;
    } else {
        float* base = xzT + d * RT + rq;
        float4 v = *(const float4*)base;
        float4 o;
        o.x = __fdividef(v.x, 1.f + __expf(-v.x));
        o.y = __fdividef(v.y, 1.f + __expf(-v.y));
        o.z = __fdividef(v.z, 1.f + __expf(-v.z));
        o.w = __fdividef(v.w, 1.f + __expf(-v.w));
        *(float4*)base = o;
    }
}

// ---------------------------------------------------------------------------
// K4: skinny GEMM  xdT[m][row] = sum_k xproj_w[m][k] * xcT[k][row]
// M=44 (rows 0-11 dtr, 12-27 B, 28-43 C), N=8192, K=384.
__global__ __launch_bounds__(512) void xproj_gemm(const float* __restrict__ xcT,
                                                  const float* __restrict__ aw,
                                                  float* __restrict__ xdT) {
    __shared__ float Bs[32][64];
    int col0 = blockIdx.x * 64;
    int tid = threadIdx.x;
    int col = tid & 63, mg = tid >> 6;          // mg wave-uniform -> scalar A loads
    int mb = blockIdx.y * 24 + mg * 3;
    const float* a0 = aw + min(mb + 0, 43) * DI;
    const float* a1 = aw + min(mb + 1, 43) * DI;
    const float* a2 = aw + min(mb + 2, 43) * DI;
    float acc0 = 0.f, acc1 = 0.f, acc2 = 0.f;
    int ks = tid >> 4, c4 = (tid & 15) * 4;
    for (int k0 = 0; k0 < DI; k0 += 32) {
        *(float4*)&Bs[ks][c4] = *(const float4*)&xcT[(k0 + ks) * RT + col0 + c4];
        __syncthreads();
#pragma unroll
        for (int k = 0; k < 32; ++k) {
            float bv = Bs[k][col];
            acc0 = fmaf(a0[k0 + k], bv, acc0);
            acc1 = fmaf(a1[k0 + k], bv, acc1);
            acc2 = fmaf(a2[k0 + k], bv, acc2);
        }
        __syncthreads();
    }
    if (mb + 0 < 44) xdT[(mb + 0) * RT + col0 + col] = acc0;
    if (mb + 1 < 44) xdT[(mb + 1) * RT + col0 + col] = acc1;
    if (mb + 2 < 44) xdT[(mb + 2) * RT + col0 + col] = acc2;
}

// ---------------------------------------------------------------------------
// K5a: per-segment scan from h=0; dt computed inline from dtr rows of xdT.
// Emits P = prod(dA), Hf = final h. grid (16 seg, 24 dblk, 8 b), block 256.
__global__ __launch_bounds__(256) void scan_part1(const float* __restrict__ xdT,
                                                  const float* __restrict__ xcT,
                                                  const float* __restrict__ dtw,
                                                  const float* __restrict__ dtb,
                                                  const float* __restrict__ A_log,
                                                  float* __restrict__ P,
                                                  float* __restrict__ Hf) {
    __shared__ float dt_s[16][17], g_s[16][17], B_s[16][17];
    __shared__ float dtr_s[12][17];
    __shared__ float dtw_s[192];
    __shared__ float dtb_s[16];
    int seg = blockIdx.x, d0 = blockIdx.y * 16, b = blockIdx.z;
    int row0 = b * LL + seg * SEGL;
    int tid = threadIdx.x;
    int lane = tid & 63;
    int n = lane & 15;
    int dl = ((tid >> 6) << 2) | (lane >> 4);
    int tdd = tid >> 4, ti = tid & 15;
    if (tid < 192) dtw_s[tid] = dtw[d0 * DT_RANK + tid];
    if (tid < 16)  dtb_s[tid] = dtb[d0 + tid];
    float a = -__expf(A_log[(d0 + dl) * NS + n]);
    float h = 0.f, Pacc = 1.f;
    for (int ch = 0; ch < 4; ++ch) {
        int r = row0 + ch * 16;
        float xv = xcT[(d0 + tdd) * RT + r + ti];
        B_s[tdd][ti] = xdT[(12 + tdd) * RT + r + ti];
        if (tid < 192) dtr_s[tid >> 4][ti] = xdT[(tid >> 4) * RT + r + ti];
        __syncthreads();     // dtr_s/dtw_s ready; prev inner-loop reads done
        float acc = dtb_s[tdd];
#pragma unroll
        for (int rr = 0; rr < DT_RANK; ++rr)
            acc = fmaf(dtr_s[rr][ti], dtw_s[tdd * DT_RANK + rr], acc);
        float dtv = fmaxf(acc, 0.f) + __logf(1.f + __expf(-fabsf(acc)));
        dt_s[tdd][ti] = dtv;
        g_s[tdd][ti]  = dtv * xv;
        __syncthreads();     // dt_s/g_s/B_s ready
#pragma unroll
        for (int i = 0; i < 16; ++i) {
            float e = __expf(dt_s[dl][i] * a);
            Pacc *= e;
            h = fmaf(e, h, g_s[dl][i] * B_s[n][i]);
        }
        __syncthreads();     // inner reads done before next stage overwrites
    }
    int idx = ((seg * BB + b) * DI + d0 + dl) * NS + n;
    P[idx] = Pacc;
    Hf[idx] = h;
}

// ---------------------------------------------------------------------------
// K5b: rescan each segment; h_init computed in-block by folding the earlier
// segments' (P,Hf) summaries (replaces the scan_mid dispatch). dt inline.
// Per-step h*C to LDS; per-chunk 16-wide n-reduction + y epilogue.
__global__ __launch_bounds__(256) void scan_part2(const float* __restrict__ xdT,
                                                  const float* __restrict__ xcT,
                                                  const float* __restrict__ zsT,
                                                  const float* __restrict__ dtw,
                                                  const float* __restrict__ dtb,
                                                  const float* __restrict__ P,
                                                  const float* __restrict__ Hf,
                                                  const float* __restrict__ A_log,
                                                  const float* __restrict__ Dp,
                                                  float* __restrict__ yT) {
    __shared__ float dt_s[16][17], g_s[16][17], B_s[16][17], C_s[16][17];
    __shared__ float dtr_s[12][17];
    __shared__ float hc_s[16][16][17];   // [dl][i][n]; 2-way bank alias only (free)
    __shared__ float dtw_s[192];
    __shared__ float dtb_s[16];
    int seg = blockIdx.x, d0 = blockIdx.y * 16, b = blockIdx.z;
    int row0 = b * LL + seg * SEGL;
    int tid = threadIdx.x;
    int lane = tid & 63;
    int n = lane & 15;
    int dl = ((tid >> 6) << 2) | (lane >> 4);
    int d = d0 + dl;
    int tdd = tid >> 4, ti = tid & 15;
    if (tid < 192) dtw_s[tid] = dtw[d0 * DT_RANK + tid];
    if (tid < 16)  dtb_s[tid] = dtb[d0 + tid];
    float a = -__expf(A_log[d * NS + n]);
    float Dpw = Dp[d0 + tdd];            // for the writer role (tdd,ti)
    // h_init: fold earlier segments' summaries (coalesced loads)
    float h = 0.f;
    for (int s = 0; s < seg; ++s) {
        int off = ((s * BB + b) * DI + d) * NS + n;
        h = fmaf(P[off], h, Hf[off]);
    }
    for (int ch = 0; ch < 4; ++ch) {
        int r = row0 + ch * 16;
        float xv  = xcT[(d0 + tdd) * RT + r + ti];
        float zsv = zsT[(d0 + tdd) * RT + r + ti];
        B_s[tdd][ti] = xdT[(12 + tdd) * RT + r + ti];
        C_s[tdd][ti] = xdT[(28 + tdd) * RT + r + ti];
        if (tid < 192) dtr_s[tid >> 4][ti] = xdT[(tid >> 4) * RT + r + ti];
        __syncthreads();
        float acc = dtb_s[tdd];
#pragma unroll
        for (int rr = 0; rr < DT_RANK; ++rr)
            acc = fmaf(dtr_s[rr][ti], dtw_s[tdd * DT_RANK + rr], acc);
        float dtv = fmaxf(acc, 0.f) + __logf(1.f + __expf(-fabsf(acc)));
        dt_s[tdd][ti] = dtv;
        g_s[tdd][ti]  = dtv * xv;
        __syncthreads();
#pragma unroll
        for (int i = 0; i < 16; ++i) {
            float e = __expf(dt_s[dl][i] * a);
            h = fmaf(e, h, g_s[dl][i] * B_s[n][i]);
            hc_s[dl][i][n] = h * C_s[n][i];
        }
        __syncthreads();
        // thread (tdd,ti) owns element (d=d0+tdd, row=r+ti); xv/zsv in regs
        float s0 = 0.f, s1 = 0.f, s2 = 0.f, s3 = 0.f;
#pragma unroll
        for (int q = 0; q < 4; ++q) {
            s0 += hc_s[tdd][ti][q];
            s1 += hc_s[tdd][ti][4 + q];
            s2 += hc_s[tdd][ti][8 + q];
            s3 += hc_s[tdd][ti][12 + q];
        }
        float ssum = (s0 + s1) + (s2 + s3);
        yT[(d0 + tdd) * RT + r + ti] = fmaf(xv, Dpw, ssum) * zsv;
    }
}

// ---------------------------------------------------------------------------
// K6: out[b, c, l] = sum_d yT[d, row] * out_w[c, d]
// 64x64 tile, 4x4 microtile, 256 threads. grid (128, 3).
// block=256, grid 384 = 1.5 blocks/CU: more waves in flight beat the
// "even 256-block" (128,2) config, which stalled at 10% occupancy (R4).
__global__ __launch_bounds__(256) void gemm_out(const float* __restrict__ yT,
                                                const float* __restrict__ out_w,
                                                float* __restrict__ out) {
    __shared__ float As[16][68];  // [k][row]
    __shared__ float Bs[16][68];  // [k][c]
    int r0 = blockIdx.x * 64;
    int c0 = blockIdx.y * 64;
    int b = r0 >> 10, l0 = r0 & 1023;
    int tid = threadIdx.x;
    int tx = tid & 15;   // -> row
    int ty = tid >> 4;   // -> c
    float acc[4][4] = {};  // [cc][rc]
    for (int k0 = 0; k0 < DI; k0 += 16) {
        {   // A: yT[k0+k, r0+r..] -> As[k][r]
            int k = tid >> 4, r4 = (tid & 15) * 4;
            *(float4*)&As[k][r4] = *(const float4*)&yT[(k0 + k) * RT + r0 + r4];
        }
        {   // B: out_w[c0+c, k0+kc..] -> Bs[kc][c]
            int c = tid >> 2, kc = (tid & 3) * 4;
            float4 v = *(const float4*)&out_w[(c0 + c) * DI + k0 + kc];
            Bs[kc + 0][c] = v.x; Bs[kc + 1][c] = v.y;
            Bs[kc + 2][c] = v.z; Bs[kc + 3][c] = v.w;
        }
        __syncthreads();
#pragma unroll
        for (int k = 0; k < 16; ++k) {
            float4 av = *(const float4*)&As[k][tx * 4];
            float4 bv = *(const float4*)&Bs[k][ty * 4];
            acc[0][0] = fmaf(bv.x, av.x, acc[0][0]);
            acc[0][1] = fmaf(bv.x, av.y, acc[0][1]);
            acc[0][2] = fmaf(bv.x, av.z, acc[0][2]);
            acc[0][3] = fmaf(bv.x, av.w, acc[0][3]);
            acc[1][0] = fmaf(bv.y, av.x, acc[1][0]);
            acc[1][1] = fmaf(bv.y, av.y, acc[1][1]);
            acc[1][2] = fmaf(bv.y, av.z, acc[1][2]);
            acc[1][3] = fmaf(bv.y, av.w, acc[1][3]);
            acc[2][0] = fmaf(bv.z, av.x, acc[2][0]);
            acc[2][1] = fmaf(bv.z, av.y, acc[2][1]);
            acc[2][2] = fmaf(bv.z, av.z, acc[2][2]);
            acc[2][3] = fmaf(bv.z, av.w, acc[2][3]);
            acc[3][0] = fmaf(bv.w, av.x, acc[3][0]);
            acc[3][1] = fmaf(bv.w, av.y, acc[3][1]);
            acc[3][2] = fmaf(bv.w, av.z, acc[3][2]);
            acc[3][3] = fmaf(bv.w, av.w, acc[3][3]);
        }
        __syncthreads();
    }
    float* ob = out + b * CC * LL;
#pragma unroll
    for (int ic = 0; ic < 4; ++ic) {
        float4 o;
        o.x = acc[ic][0]; o.y = acc[ic][1]; o.z = acc[ic][2]; o.w = acc[ic][3];
        *(float4*)&ob[(c0 + ty * 4 + ic) * LL + l0 + tx * 4] = o;
    }
}

// ---------------------------------------------------------------------------
extern "C" void kernel_launch(void* const* d_in, const int* in_sizes, int n_in,
                              void* d_out, int out_size, void* d_ws, size_t ws_size,
                              hipStream_t stream) {
    const float* x         = (const float*)d_in[0];
    const float* proj_w    = (const float*)d_in[1];
    const float* proj_b    = (const float*)d_in[2];
    const float* in_proj_w = (const float*)d_in[3];
    const float* conv_w    = (const float*)d_in[4];
    const float* conv_b    = (const float*)d_in[5];
    const float* xproj_w   = (const float*)d_in[6];
    const float* dtproj_w  = (const float*)d_in[7];
    const float* dtproj_b  = (const float*)d_in[8];
    const float* A_log     = (const float*)d_in[9];
    const float* Dp        = (const float*)d_in[10];
    const float* out_w     = (const float*)d_in[11];
    float* out = (float*)d_out;

    float* ws    = (float*)d_ws;
    float* W2    = ws;                    // 147456
    float* bias2 = W2 + 147456;           // 768
    float* xzT   = bias2 + 768;           // 768*8192 = 6291456
    float* xcT   = xzT + 6291456;         // 3145728
    float* yT    = xcT + 3145728;         // 3145728
    float* xdT   = yT + 3145728;          // 44*8192 = 360448 (0-11 dtr, 12-27 B, 28-43 C)
    float* P     = xdT + 360448;          // 786432
    float* Hf    = P + 786432;            // 786432
    float* zsT   = xzT + DI * RT;         // z half, silu'd in place by conv_silu

    fuse_w_kernel<<<768, 192, 0, stream>>>(in_proj_w, proj_w, proj_b, W2, bias2);
    gemm_xz<<<dim3(64, 8), 256, 0, stream>>>(x, W2, bias2, xzT);
    conv_silu<<<6144, 256, 0, stream>>>(xzT, conv_w, conv_b, xcT);
    xproj_gemm<<<dim3(128, 2), 512, 0, stream>>>(xcT, xproj_w, xdT);
    scan_part1<<<dim3(16, 24, 8), 256, 0, stream>>>(xdT, xcT, dtproj_w, dtproj_b,
                                                    A_log, P, Hf);
    scan_part2<<<dim3(16, 24, 8), 256, 0, stream>>>(xdT, xcT, zsT, dtproj_w, dtproj_b,
                                                    P, Hf, A_log, Dp, yT);
    gemm_out<<<dim3(128, 3), 256, 0, stream>>>(yT, out_w, out);
}

// Round 6
// 236.935 us; speedup vs baseline: 1.0884x; 1.0252x over previous
//
#include <hip/hip_runtime.h>
#include <math.h>

// Problem constants (B=8, C=192, H=W=32)
#define BB 8
#define CC 192
#define LL 1024
#define RT 8192         // total rows = BB*LL
#define DI 384          // d_inner
#define DT_RANK 12
#define NS 16           // D_STATE
#define NSEG 16
#define SEGL 64

// ---------------------------------------------------------------------------
// K1: W2[j,c'] = sum_c in_proj_w[j,c]*proj_w[c,c'];  bias2[j] = in_proj_w[j,:]·proj_b
__global__ void fuse_w_kernel(const float* __restrict__ in_proj_w,
                              const float* __restrict__ proj_w,
                              const float* __restrict__ proj_b,
                              float* __restrict__ W2, float* __restrict__ bias2) {
    int j = blockIdx.x;
    int cp = threadIdx.x;
    __shared__ float wrow[CC];
    wrow[cp] = in_proj_w[j * CC + cp];
    __syncthreads();
    float acc = 0.f;
#pragma unroll 4
    for (int c = 0; c < CC; ++c) acc = fmaf(wrow[c], proj_w[c * CC + cp], acc);
    W2[j * CC + cp] = acc;
    if (cp == 0) {
        float b = 0.f;
        for (int c = 0; c < CC; ++c) b = fmaf(wrow[c], proj_b[c], b);
        bias2[j] = b;
    }
}

// ---------------------------------------------------------------------------
// K2: xzT[j, row] = sum_c x[b, c, l] * W2[j, c] + bias2[j]   (row = b*1024+l)
// 128 rows x 96 j tile, 256 threads, microtile 6j x (4+4) rows split at +64
// so A-fragment reads are lane-consecutive float4 (conflict-free; the old
// tx*8 layout was 4-way bank-conflicted: 3.4M conflicts/dispatch in R5).
// z-half blocks (j0>=384) apply silu in the epilogue -> zsT directly.
__global__ __launch_bounds__(256) void gemm_xz(const float* __restrict__ x,
                                               const float* __restrict__ W2,
                                               const float* __restrict__ bias2,
                                               float* __restrict__ xzT) {
    __shared__ float As[16][132];  // [k][row]
    __shared__ float Bs[16][100];  // [k][j]
    int r0 = blockIdx.x * 128;
    int j0 = blockIdx.y * 96;
    int b  = r0 >> 10;
    int l0 = r0 & 1023;
    int tid = threadIdx.x;
    int tx = tid & 15;   // row quad (x2, split 64 apart)
    int ty = tid >> 4;   // j sextet
    float acc[6][8] = {};
    const float* xb = x + b * CC * LL;
    for (int k0 = 0; k0 < CC; k0 += 16) {
#pragma unroll
        for (int it = 0; it < 2; ++it) {     // A: 16k x 128row = 512 float4
            int idx = tid + it * 256;
            int k = idx >> 5, l4 = (idx & 31) * 4;
            *(float4*)&As[k][l4] = *(const float4*)&xb[(k0 + k) * LL + l0 + l4];
        }
#pragma unroll
        for (int it = 0; it < 2; ++it) {     // B: 96j x 16k = 384 float4
            int idx = tid + it * 256;
            if (idx < 384) {
                int j = idx >> 2, kq = (idx & 3) * 4;
                float4 v = *(const float4*)&W2[(j0 + j) * CC + k0 + kq];
                Bs[kq + 0][j] = v.x; Bs[kq + 1][j] = v.y;
                Bs[kq + 2][j] = v.z; Bs[kq + 3][j] = v.w;
            }
        }
        __syncthreads();
#pragma unroll
        for (int k = 0; k < 16; ++k) {
            float4 a0 = *(const float4*)&As[k][tx * 4];        // rows tx*4..+3
            float4 a1 = *(const float4*)&As[k][64 + tx * 4];   // rows 64+tx*4..+3
            float ar[8] = {a0.x, a0.y, a0.z, a0.w, a1.x, a1.y, a1.z, a1.w};
            float br[6];
#pragma unroll
            for (int q = 0; q < 6; ++q) br[q] = Bs[k][ty * 6 + q];
#pragma unroll
            for (int jc = 0; jc < 6; ++jc)
#pragma unroll
                for (int rc = 0; rc < 8; ++rc)
                    acc[jc][rc] = fmaf(br[jc], ar[rc], acc[jc][rc]);
        }
        __syncthreads();
    }
    bool is_z = (j0 >= DI);
#pragma unroll
    for (int jc = 0; jc < 6; ++jc) {
        int j = j0 + ty * 6 + jc;
        float bval = bias2[j];
        float o[8];
#pragma unroll
        for (int rc = 0; rc < 8; ++rc) o[rc] = acc[jc][rc] + bval;
        if (is_z) {
#pragma unroll
            for (int rc = 0; rc < 8; ++rc)
                o[rc] = __fdividef(o[rc], 1.f + __expf(-o[rc]));
        }
        float4 o0 = make_float4(o[0], o[1], o[2], o[3]);
        float4 o1 = make_float4(o[4], o[5], o[6], o[7]);
        *(float4*)&xzT[j * RT + r0 + tx * 4]      = o0;
        *(float4*)&xzT[j * RT + r0 + 64 + tx * 4] = o1;
    }
}

// ---------------------------------------------------------------------------
// K3: skinny GEMM with fused causal depthwise conv (k=4) + silu in staging.
// xdT[m][row] = sum_k xproj_w[m][k] * silu(conv(xz))[k][row]
// Staging reads raw xzT x-half (+3-col halo), computes conv+silu into LDS,
// and side-writes xcT (blockIdx.y==0 only) for the scan kernels.
// M=44 (rows 0-11 dtr, 12-27 B, 28-43 C), N=8192, K=384. grid (128,2), 512 thr.
__global__ __launch_bounds__(512) void xproj_conv_gemm(const float* __restrict__ xzT,
                                                       const float* __restrict__ conv_w,
                                                       const float* __restrict__ conv_b,
                                                       const float* __restrict__ aw,
                                                       float* __restrict__ xcT,
                                                       float* __restrict__ xdT) {
    __shared__ float Bs[32][64];
    int col0 = blockIdx.x * 64;
    int tid = threadIdx.x;
    int col = tid & 63, mg = tid >> 6;          // mg wave-uniform -> scalar A loads
    int mb = blockIdx.y * 24 + mg * 3;
    const float* a0 = aw + min(mb + 0, 43) * DI;
    const float* a1 = aw + min(mb + 1, 43) * DI;
    const float* a2 = aw + min(mb + 2, 43) * DI;
    float acc0 = 0.f, acc1 = 0.f, acc2 = 0.f;
    int ks = tid >> 4, c4 = (tid & 15) * 4;
    bool atL0 = ((col0 & 1023) == 0) && (c4 == 0);   // conv zero-pad boundary
    bool wr = (blockIdx.y == 0);
    for (int k0 = 0; k0 < DI; k0 += 32) {
        int dch = k0 + ks;
        const float* src = xzT + (size_t)dch * RT + col0 + c4;
        float4 cur = *(const float4*)src;
        float4 prev = make_float4(0.f, 0.f, 0.f, 0.f);
        if (!atL0) prev = *(const float4*)(src - 4);
        float4 w4 = *(const float4*)&conv_w[dch * 4];   // w0=x w1=y w2=z w3=w
        float bb = conv_b[dch];
        float v0 = bb + w4.w * cur.x + w4.z * prev.w + w4.y * prev.z + w4.x * prev.y;
        float v1 = bb + w4.w * cur.y + w4.z * cur.x  + w4.y * prev.w + w4.x * prev.z;
        float v2 = bb + w4.w * cur.z + w4.z * cur.y  + w4.y * cur.x  + w4.x * prev.w;
        float v3 = bb + w4.w * cur.w + w4.z * cur.z  + w4.y * cur.y  + w4.x * cur.x;
        float4 o;
        o.x = __fdividef(v0, 1.f + __expf(-v0));
        o.y = __fdividef(v1, 1.f + __expf(-v1));
        o.z = __fdividef(v2, 1.f + __expf(-v2));
        o.w = __fdividef(v3, 1.f + __expf(-v3));
        *(float4*)&Bs[ks][c4] = o;
        if (wr) *(float4*)&xcT[(size_t)dch * RT + col0 + c4] = o;
        __syncthreads();
#pragma unroll
        for (int k = 0; k < 32; ++k) {
            float bv = Bs[k][col];
            acc0 = fmaf(a0[k0 + k], bv, acc0);
            acc1 = fmaf(a1[k0 + k], bv, acc1);
            acc2 = fmaf(a2[k0 + k], bv, acc2);
        }
        __syncthreads();
    }
    if (mb + 0 < 44) xdT[(mb + 0) * RT + col0 + col] = acc0;
    if (mb + 1 < 44) xdT[(mb + 1) * RT + col0 + col] = acc1;
    if (mb + 2 < 44) xdT[(mb + 2) * RT + col0 + col] = acc2;
}

// ---------------------------------------------------------------------------
// K4a: per-segment scan from h=0; dt computed inline from dtr rows of xdT.
// Emits P = prod(dA), Hf = final h. grid (16 seg, 24 dblk, 8 b), block 256.
__global__ __launch_bounds__(256) void scan_part1(const float* __restrict__ xdT,
                                                  const float* __restrict__ xcT,
                                                  const float* __restrict__ dtw,
                                                  const float* __restrict__ dtb,
                                                  const float* __restrict__ A_log,
                                                  float* __restrict__ P,
                                                  float* __restrict__ Hf) {
    __shared__ float dt_s[16][17], g_s[16][17], B_s[16][17];
    __shared__ float dtr_s[12][17];
    __shared__ float dtw_s[192];
    __shared__ float dtb_s[16];
    int seg = blockIdx.x, d0 = blockIdx.y * 16, b = blockIdx.z;
    int row0 = b * LL + seg * SEGL;
    int tid = threadIdx.x;
    int lane = tid & 63;
    int n = lane & 15;
    int dl = ((tid >> 6) << 2) | (lane >> 4);
    int tdd = tid >> 4, ti = tid & 15;
    if (tid < 192) dtw_s[tid] = dtw[d0 * DT_RANK + tid];
    if (tid < 16)  dtb_s[tid] = dtb[d0 + tid];
    float a = -__expf(A_log[(d0 + dl) * NS + n]);
    float h = 0.f, Pacc = 1.f;
    for (int ch = 0; ch < 4; ++ch) {
        int r = row0 + ch * 16;
        float xv = xcT[(d0 + tdd) * RT + r + ti];
        B_s[tdd][ti] = xdT[(12 + tdd) * RT + r + ti];
        if (tid < 192) dtr_s[tid >> 4][ti] = xdT[(tid >> 4) * RT + r + ti];
        __syncthreads();     // dtr_s ready; prev inner-loop reads done
        float acc = dtb_s[tdd];
#pragma unroll
        for (int rr = 0; rr < DT_RANK; ++rr)
            acc = fmaf(dtr_s[rr][ti], dtw_s[tdd * DT_RANK + rr], acc);
        float dtv = fmaxf(acc, 0.f) + __logf(1.f + __expf(-fabsf(acc)));
        dt_s[tdd][ti] = dtv;
        g_s[tdd][ti]  = dtv * xv;
        __syncthreads();     // dt_s/g_s/B_s ready
#pragma unroll
        for (int i = 0; i < 16; ++i) {
            float e = __expf(dt_s[dl][i] * a);
            Pacc *= e;
            h = fmaf(e, h, g_s[dl][i] * B_s[n][i]);
        }
        __syncthreads();     // inner reads done before next stage overwrites
    }
    int idx = ((seg * BB + b) * DI + d0 + dl) * NS + n;
    P[idx] = Pacc;
    Hf[idx] = h;
}

// ---------------------------------------------------------------------------
// K4b: rescan each segment; h_init computed in-block by folding the earlier
// segments' (P,Hf) summaries. dt inline. Per-step h*C to LDS; per-chunk
// 16-wide n-reduction + y epilogue.
__global__ __launch_bounds__(256) void scan_part2(const float* __restrict__ xdT,
                                                  const float* __restrict__ xcT,
                                                  const float* __restrict__ zsT,
                                                  const float* __restrict__ dtw,
                                                  const float* __restrict__ dtb,
                                                  const float* __restrict__ P,
                                                  const float* __restrict__ Hf,
                                                  const float* __restrict__ A_log,
                                                  const float* __restrict__ Dp,
                                                  float* __restrict__ yT) {
    __shared__ float dt_s[16][17], g_s[16][17], B_s[16][17], C_s[16][17];
    __shared__ float dtr_s[12][17];
    __shared__ float hc_s[16][16][17];   // [dl][i][n]; 2-way bank alias only (free)
    __shared__ float dtw_s[192];
    __shared__ float dtb_s[16];
    int seg = blockIdx.x, d0 = blockIdx.y * 16, b = blockIdx.z;
    int row0 = b * LL + seg * SEGL;
    int tid = threadIdx.x;
    int lane = tid & 63;
    int n = lane & 15;
    int dl = ((tid >> 6) << 2) | (lane >> 4);
    int d = d0 + dl;
    int tdd = tid >> 4, ti = tid & 15;
    if (tid < 192) dtw_s[tid] = dtw[d0 * DT_RANK + tid];
    if (tid < 16)  dtb_s[tid] = dtb[d0 + tid];
    float a = -__expf(A_log[d * NS + n]);
    float Dpw = Dp[d0 + tdd];            // for the writer role (tdd,ti)
    // h_init: fold earlier segments' summaries (coalesced loads)
    float h = 0.f;
    for (int s = 0; s < seg; ++s) {
        int off = ((s * BB + b) * DI + d) * NS + n;
        h = fmaf(P[off], h, Hf[off]);
    }
    for (int ch = 0; ch < 4; ++ch) {
        int r = row0 + ch * 16;
        float xv  = xcT[(d0 + tdd) * RT + r + ti];
        float zsv = zsT[(d0 + tdd) * RT + r + ti];
        B_s[tdd][ti] = xdT[(12 + tdd) * RT + r + ti];
        C_s[tdd][ti] = xdT[(28 + tdd) * RT + r + ti];
        if (tid < 192) dtr_s[tid >> 4][ti] = xdT[(tid >> 4) * RT + r + ti];
        __syncthreads();
        float acc = dtb_s[tdd];
#pragma unroll
        for (int rr = 0; rr < DT_RANK; ++rr)
            acc = fmaf(dtr_s[rr][ti], dtw_s[tdd * DT_RANK + rr], acc);
        float dtv = fmaxf(acc, 0.f) + __logf(1.f + __expf(-fabsf(acc)));
        dt_s[tdd][ti] = dtv;
        g_s[tdd][ti]  = dtv * xv;
        __syncthreads();
#pragma unroll
        for (int i = 0; i < 16; ++i) {
            float e = __expf(dt_s[dl][i] * a);
            h = fmaf(e, h, g_s[dl][i] * B_s[n][i]);
            hc_s[dl][i][n] = h * C_s[n][i];
        }
        __syncthreads();
        // thread (tdd,ti) owns element (d=d0+tdd, row=r+ti); xv/zsv in regs
        float s0 = 0.f, s1 = 0.f, s2 = 0.f, s3 = 0.f;
#pragma unroll
        for (int q = 0; q < 4; ++q) {
            s0 += hc_s[tdd][ti][q];
            s1 += hc_s[tdd][ti][4 + q];
            s2 += hc_s[tdd][ti][8 + q];
            s3 += hc_s[tdd][ti][12 + q];
        }
        float ssum = (s0 + s1) + (s2 + s3);
        yT[(d0 + tdd) * RT + r + ti] = fmaf(xv, Dpw, ssum) * zsv;
    }
}

// ---------------------------------------------------------------------------
// K5: out[b, c, l] = sum_d yT[d, row] * out_w[c, d]
// 64x64 tile, 4x4 microtile, 256 threads. grid (128, 3).
__global__ __launch_bounds__(256) void gemm_out(const float* __restrict__ yT,
                                                const float* __restrict__ out_w,
                                                float* __restrict__ out) {
    __shared__ float As[16][68];  // [k][row]
    __shared__ float Bs[16][68];  // [k][c]
    int r0 = blockIdx.x * 64;
    int c0 = blockIdx.y * 64;
    int b = r0 >> 10, l0 = r0 & 1023;
    int tid = threadIdx.x;
    int tx = tid & 15;   // -> row
    int ty = tid >> 4;   // -> c
    float acc[4][4] = {};  // [cc][rc]
    for (int k0 = 0; k0 < DI; k0 += 16) {
        {   // A: yT[k0+k, r0+r..] -> As[k][r]
            int k = tid >> 4, r4 = (tid & 15) * 4;
            *(float4*)&As[k][r4] = *(const float4*)&yT[(k0 + k) * RT + r0 + r4];
        }
        {   // B: out_w[c0+c, k0+kc..] -> Bs[kc][c]
            int c = tid >> 2, kc = (tid & 3) * 4;
            float4 v = *(const float4*)&out_w[(c0 + c) * DI + k0 + kc];
            Bs[kc + 0][c] = v.x; Bs[kc + 1][c] = v.y;
            Bs[kc + 2][c] = v.z; Bs[kc + 3][c] = v.w;
        }
        __syncthreads();
#pragma unroll
        for (int k = 0; k < 16; ++k) {
            float4 av = *(const float4*)&As[k][tx * 4];
            float4 bv = *(const float4*)&Bs[k][ty * 4];
            acc[0][0] = fmaf(bv.x, av.x, acc[0][0]);
            acc[0][1] = fmaf(bv.x, av.y, acc[0][1]);
            acc[0][2] = fmaf(bv.x, av.z, acc[0][2]);
            acc[0][3] = fmaf(bv.x, av.w, acc[0][3]);
            acc[1][0] = fmaf(bv.y, av.x, acc[1][0]);
            acc[1][1] = fmaf(bv.y, av.y, acc[1][1]);
            acc[1][2] = fmaf(bv.y, av.z, acc[1][2]);
            acc[1][3] = fmaf(bv.y, av.w, acc[1][3]);
            acc[2][0] = fmaf(bv.z, av.x, acc[2][0]);
            acc[2][1] = fmaf(bv.z, av.y, acc[2][1]);
            acc[2][2] = fmaf(bv.z, av.z, acc[2][2]);
            acc[2][3] = fmaf(bv.z, av.w, acc[2][3]);
            acc[3][0] = fmaf(bv.w, av.x, acc[3][0]);
            acc[3][1] = fmaf(bv.w, av.y, acc[3][1]);
            acc[3][2] = fmaf(bv.w, av.z, acc[3][2]);
            acc[3][3] = fmaf(bv.w, av.w, acc[3][3]);
        }
        __syncthreads();
    }
    float* ob = out + b * CC * LL;
#pragma unroll
    for (int ic = 0; ic < 4; ++ic) {
        float4 o;
        o.x = acc[ic][0]; o.y = acc[ic][1]; o.z = acc[ic][2]; o.w = acc[ic][3];
        *(float4*)&ob[(c0 + ty * 4 + ic) * LL + l0 + tx * 4] = o;
    }
}

// ---------------------------------------------------------------------------
extern "C" void kernel_launch(void* const* d_in, const int* in_sizes, int n_in,
                              void* d_out, int out_size, void* d_ws, size_t ws_size,
                              hipStream_t stream) {
    const float* x         = (const float*)d_in[0];
    const float* proj_w    = (const float*)d_in[1];
    const float* proj_b    = (const float*)d_in[2];
    const float* in_proj_w = (const float*)d_in[3];
    const float* conv_w    = (const float*)d_in[4];
    const float* conv_b    = (const float*)d_in[5];
    const float* xproj_w   = (const float*)d_in[6];
    const float* dtproj_w  = (const float*)d_in[7];
    const float* dtproj_b  = (const float*)d_in[8];
    const float* A_log     = (const float*)d_in[9];
    const float* Dp        = (const float*)d_in[10];
    const float* out_w     = (const float*)d_in[11];
    float* out = (float*)d_out;

    float* ws    = (float*)d_ws;
    float* W2    = ws;                    // 147456
    float* bias2 = W2 + 147456;           // 768
    float* xzT   = bias2 + 768;           // 768*8192 = 6291456 (x raw, z silu'd)
    float* xcT   = xzT + 6291456;         // 3145728
    float* yT    = xcT + 3145728;         // 3145728
    float* xdT   = yT + 3145728;          // 44*8192 = 360448 (0-11 dtr, 12-27 B, 28-43 C)
    float* P     = xdT + 360448;          // 786432
    float* Hf    = P + 786432;            // 786432
    float* zsT   = xzT + DI * RT;         // z half, silu applied by gemm_xz epilogue

    fuse_w_kernel<<<768, 192, 0, stream>>>(in_proj_w, proj_w, proj_b, W2, bias2);
    gemm_xz<<<dim3(64, 8), 256, 0, stream>>>(x, W2, bias2, xzT);
    xproj_conv_gemm<<<dim3(128, 2), 512, 0, stream>>>(xzT, conv_w, conv_b,
                                                      xproj_w, xcT, xdT);
    scan_part1<<<dim3(16, 24, 8), 256, 0, stream>>>(xdT, xcT, dtproj_w, dtproj_b,
                                                    A_log, P, Hf);
    scan_part2<<<dim3(16, 24, 8), 256, 0, stream>>>(xdT, xcT, zsT, dtproj_w, dtproj_b,
                                                    P, Hf, A_log, Dp, yT);
    gemm_out<<<dim3(128, 3), 256, 0, stream>>>(yT, out_w, out);
}